// Round 3
// baseline (11533.733 us; speedup 1.0000x reference)
//
#include <hip/hip_runtime.h>
#include <math.h>

#define NEGV -1e9f
#define SK_TAU 0.05f

// =====================================================================
// inv column L1 norm: inv[b*256+m] = 1 / max(sum_n |A[b,n,m]|, 1e-12)
// =====================================================================
__global__ __launch_bounds__(256) void colnorm_k(const float* __restrict__ A,
                                                 float* __restrict__ inv)
{
    int idx = blockIdx.x * 256 + threadIdx.x;   // b*256 + m, 8192 total
    int b = idx >> 8, m = idx & 255;
    const float* p = A + (long long)b * 65536 + m;
    float s = 0.f;
    #pragma unroll 8
    for (int n = 0; n < 256; ++n) s += fabsf(p[n * 256]);
    inv[idx] = 1.f / fmaxf(s, 1e-12f);
}

// =====================================================================
// fp32 GEMM: C[z] = epi( A[z] @ B[z] )   (fp32 accumulate)
//   TA=false: A is MxK row-major.  TA=true: A is KxM row-major (use A^T).
//   TB=false: B is KxN row-major.  TB=true: B is NxK row-major (use B^T).
// Tile 128x128x16, 256 threads, 8x8 per thread.
// Epilogue: (+bias[n]) -> relu -> (*rowscale[row]) -> (+=C | =C)
// =====================================================================
#define BMt 128
#define BNt 128
#define BKt 16
#define LDT 132

template <bool TA, bool TB>
__global__ __launch_bounds__(256, 2) void gemm_k(
    const float* __restrict__ A, const float* __restrict__ B,
    float* __restrict__ C, int M, int N, int K,
    long long sA, long long sB, long long sC,
    const float* __restrict__ bias, const float* __restrict__ rowscale,
    int relu, int acc)
{
    __shared__ float As[BKt][LDT];
    __shared__ float Bs[BKt][LDT];

    int z = blockIdx.z;
    A += (long long)z * sA;
    B += (long long)z * sB;
    C += (long long)z * sC;

    int n0 = blockIdx.x * BNt;
    int m0 = blockIdx.y * BMt;
    int tid = threadIdx.x;
    int tx = tid & 15;
    int ty = tid >> 4;

    const int ldA = TA ? M : K;
    const int ldB = TB ? K : N;

    float accv[8][8];
    #pragma unroll
    for (int i = 0; i < 8; ++i)
        #pragma unroll
        for (int j = 0; j < 8; ++j) accv[i][j] = 0.f;

    for (int k0 = 0; k0 < K; k0 += BKt) {
        if (!TA) {
            #pragma unroll
            for (int i = 0; i < 2; ++i) {
                int lin = tid + i * 256;
                int r  = lin >> 2;
                int c4 = (lin & 3) * 4;
                const float4 v = *(const float4*)(A + (long long)(m0 + r) * ldA + k0 + c4);
                As[c4 + 0][r] = v.x; As[c4 + 1][r] = v.y;
                As[c4 + 2][r] = v.z; As[c4 + 3][r] = v.w;
            }
        } else {
            #pragma unroll
            for (int i = 0; i < 2; ++i) {
                int lin = tid + i * 256;
                int kk = lin >> 5;
                int m4 = (lin & 31) * 4;
                *(float4*)&As[kk][m4] =
                    *(const float4*)(A + (long long)(k0 + kk) * ldA + m0 + m4);
            }
        }
        if (!TB) {
            #pragma unroll
            for (int i = 0; i < 2; ++i) {
                int lin = tid + i * 256;
                int kk = lin >> 5;
                int n4 = (lin & 31) * 4;
                *(float4*)&Bs[kk][n4] =
                    *(const float4*)(B + (long long)(k0 + kk) * ldB + n0 + n4);
            }
        } else {
            #pragma unroll
            for (int i = 0; i < 2; ++i) {
                int lin = tid + i * 256;
                int r  = lin >> 2;
                int c4 = (lin & 3) * 4;
                const float4 v = *(const float4*)(B + (long long)(n0 + r) * ldB + k0 + c4);
                Bs[c4 + 0][r] = v.x; Bs[c4 + 1][r] = v.y;
                Bs[c4 + 2][r] = v.z; Bs[c4 + 3][r] = v.w;
            }
        }
        __syncthreads();

        #pragma unroll
        for (int kk = 0; kk < BKt; ++kk) {
            float a[8], b[8];
            *(float4*)&a[0] = *(const float4*)&As[kk][ty * 8];
            *(float4*)&a[4] = *(const float4*)&As[kk][ty * 8 + 4];
            *(float4*)&b[0] = *(const float4*)&Bs[kk][tx * 8];
            *(float4*)&b[4] = *(const float4*)&Bs[kk][tx * 8 + 4];
            #pragma unroll
            for (int i = 0; i < 8; ++i)
                #pragma unroll
                for (int j = 0; j < 8; ++j)
                    accv[i][j] = fmaf(a[i], b[j], accv[i][j]);
        }
        __syncthreads();
    }

    #pragma unroll
    for (int i = 0; i < 8; ++i) {
        int row = m0 + ty * 8 + i;
        float rs = rowscale ? rowscale[row] : 1.f;
        float* crow = C + (long long)row * N;
        #pragma unroll
        for (int jj = 0; jj < 2; ++jj) {
            int col = n0 + tx * 8 + jj * 4;
            float4 v;
            v.x = accv[i][jj * 4 + 0]; v.y = accv[i][jj * 4 + 1];
            v.z = accv[i][jj * 4 + 2]; v.w = accv[i][jj * 4 + 3];
            if (bias) {
                v.x += bias[col + 0]; v.y += bias[col + 1];
                v.z += bias[col + 2]; v.w += bias[col + 3];
            }
            if (relu) {
                v.x = fmaxf(v.x, 0.f); v.y = fmaxf(v.y, 0.f);
                v.z = fmaxf(v.z, 0.f); v.w = fmaxf(v.w, 0.f);
            }
            v.x *= rs; v.y *= rs; v.z *= rs; v.w *= rs;
            if (acc) {
                float4 o = *(const float4*)(crow + col);
                v.x += o.x; v.y += o.y; v.z += o.z; v.w += o.w;
            }
            *(float4*)(crow + col) = v;
        }
    }
}

static void gemm(hipStream_t st, bool ta, bool tb,
                 const float* A, const float* B, float* C,
                 int M, int N, int K,
                 long long sA, long long sB, long long sC, int batch,
                 const float* bias, const float* rowscale, int relu, int acc)
{
    dim3 grid(N / BNt, M / BMt, batch), block(256);
    if (!ta && !tb)
        gemm_k<false, false><<<grid, block, 0, st>>>(A, B, C, M, N, K, sA, sB, sC, bias, rowscale, relu, acc);
    else if (ta && !tb)
        gemm_k<true, false><<<grid, block, 0, st>>>(A, B, C, M, N, K, sA, sB, sC, bias, rowscale, relu, acc);
    else
        gemm_k<false, true><<<grid, block, 0, st>>>(A, B, C, M, N, K, sA, sB, sC, bias, rowscale, relu, acc);
}

// =====================================================================
// fp64-accumulate batched GEMM for the affinity scores: C = A @ B^T.
// A: 256x2048 row-major (MxK), B: 256x2048 row-major (NxK), C: 256x256.
// The s-entries are coherent positive sums to ~450 over K=2048; fp32
// sequential accumulation loses ~6e-4 abs -> x20 by 1/tau -> 0.012 in
// sinkhorn logits. fp64 accumulators make the GEMM near-exact.
// Tile 64x64x16, 256 threads, 4x4/thread (strided frags: a[i]=As[kk][ty+16i]
// -> broadcast / 16-consecutive-bank LDS reads, conflict-free).
// =====================================================================
#define L2P 65

__global__ __launch_bounds__(256) void gemm_bt_f64(
    const float* __restrict__ A, const float* __restrict__ B,
    float* __restrict__ C, int K,
    long long sA, long long sB, long long sC)
{
    __shared__ float As[BKt][L2P];
    __shared__ float Bs[BKt][L2P];

    int z = blockIdx.z;
    A += (long long)z * sA;
    B += (long long)z * sB;
    C += (long long)z * sC;

    int n0 = blockIdx.x * 64;
    int m0 = blockIdx.y * 64;
    int tid = threadIdx.x;
    int tx = tid & 15;      // 16 cols (stride-16 x4)
    int ty = tid >> 4;      // 16 rows (stride-16 x4)

    double acc[4][4];
    #pragma unroll
    for (int i = 0; i < 4; ++i)
        #pragma unroll
        for (int j = 0; j < 4; ++j) acc[i][j] = 0.0;

    int r  = tid >> 2;            // 0..63  tile row (m or n)
    int c4 = (tid & 3) * 4;       // 0,4,8,12  k offset

    for (int k0 = 0; k0 < K; k0 += BKt) {
        {   // A tile: 64 x 16, K-contig loads, scatter to As[k][m]
            const float4 v = *(const float4*)(A + (long long)(m0 + r) * K + k0 + c4);
            As[c4 + 0][r] = v.x; As[c4 + 1][r] = v.y;
            As[c4 + 2][r] = v.z; As[c4 + 3][r] = v.w;
        }
        {   // B tile: 64 x 16 (B is NxK), scatter to Bs[k][n]
            const float4 v = *(const float4*)(B + (long long)(n0 + r) * K + k0 + c4);
            Bs[c4 + 0][r] = v.x; Bs[c4 + 1][r] = v.y;
            Bs[c4 + 2][r] = v.z; Bs[c4 + 3][r] = v.w;
        }
        __syncthreads();

        #pragma unroll
        for (int kk = 0; kk < BKt; ++kk) {
            double a[4], b[4];
            #pragma unroll
            for (int i = 0; i < 4; ++i) a[i] = (double)As[kk][ty + 16 * i];
            #pragma unroll
            for (int j = 0; j < 4; ++j) b[j] = (double)Bs[kk][tx + 16 * j];
            #pragma unroll
            for (int i = 0; i < 4; ++i)
                #pragma unroll
                for (int j = 0; j < 4; ++j)
                    acc[i][j] = fma(a[i], b[j], acc[i][j]);
        }
        __syncthreads();
    }

    #pragma unroll
    for (int i = 0; i < 4; ++i) {
        int row = m0 + ty + 16 * i;
        #pragma unroll
        for (int j = 0; j < 4; ++j) {
            int col = n0 + tx + 16 * j;
            C[(long long)row * 256 + col] = (float)acc[i][j];
        }
    }
}

// =====================================================================
// Sinkhorn row pass (axis=2 normalize). One wave per row of 256.
// =====================================================================
__global__ __launch_bounds__(256) void sk_row(float* __restrict__ S,
                                              const int* __restrict__ n1, int init)
{
    int r = blockIdx.x * 4 + (threadIdx.x >> 6);
    int lane = threadIdx.x & 63;
    int b = r >> 8, n = r & 255;
    float* p = S + (long long)r * 256;
    int lim = n1[b];
    if (n >= lim) {
        float4 neg = {NEGV, NEGV, NEGV, NEGV};
        *(float4*)(p + lane * 4) = neg;
        return;
    }
    float4 v = *(const float4*)(p + lane * 4);
    if (init) {
        v.x /= SK_TAU; v.y /= SK_TAU; v.z /= SK_TAU; v.w /= SK_TAU;
    }
    float m = fmaxf(fmaxf(v.x, v.y), fmaxf(v.z, v.w));
    #pragma unroll
    for (int off = 1; off < 64; off <<= 1) m = fmaxf(m, __shfl_xor(m, off));
    float s = expf(v.x - m) + expf(v.y - m) + expf(v.z - m) + expf(v.w - m);
    #pragma unroll
    for (int off = 1; off < 64; off <<= 1) s += __shfl_xor(s, off);
    float lse = m + logf(s);
    v.x -= lse; v.y -= lse; v.z -= lse; v.w -= lse;
    *(float4*)(p + lane * 4) = v;
}

// =====================================================================
// Sinkhorn col pass (axis=1 normalize). grid (4, B), 64 threads.
// =====================================================================
__global__ __launch_bounds__(64) void sk_col(float* __restrict__ S,
                                             const int* __restrict__ n1, int final_)
{
    int b = blockIdx.y;
    int m = blockIdx.x * 64 + threadIdx.x;
    float* base = S + (long long)b * 65536;
    int lim = n1[b];
    float vmax = -3.4e38f;
    for (int n = 0; n < 256; ++n) vmax = fmaxf(vmax, base[n * 256 + m]);
    float sum = 0.f;
    for (int n = 0; n < 256; ++n) sum += expf(base[n * 256 + m] - vmax);
    float lse = vmax + logf(sum);
    if (final_) {
        for (int n = 0; n < 256; ++n) {
            float x = base[n * 256 + m];
            base[n * 256 + m] = (n < lim) ? expf(x - lse) : 0.f;
        }
    } else {
        for (int n = 0; n < 256; ++n) {
            float x = base[n * 256 + m];
            base[n * 256 + m] = (n < lim) ? (x - lse) : NEGV;
        }
    }
}

static void sinkhorn(hipStream_t st, float* S, const int* n1)
{
    sk_row<<<2048, 256, 0, st>>>(S, n1, 1);
    for (int it = 1; it < 10; ++it) {
        if (it & 1)
            sk_col<<<dim3(4, 32), 64, 0, st>>>(S, n1, it == 9);
        else
            sk_row<<<2048, 256, 0, st>>>(S, n1, 0);
    }
}

// =====================================================================
// driver — d_ws budget EXACTLY 4 x 64 MiB. Score buffer lives in d_out;
// inv1/inv2 in the head of d_out in two windows.
// =====================================================================
extern "C" void kernel_launch(void* const* d_in, const int* in_sizes, int n_in,
                              void* d_out, int out_size, void* d_ws, size_t ws_size,
                              hipStream_t stream)
{
    const float* feat1 = (const float*)d_in[0];
    const float* feat2 = (const float*)d_in[1];
    const float* A1    = (const float*)d_in[2];
    const float* A2    = (const float*)d_in[3];
    const int*   n1    = (const int*)d_in[4];
    const float* W0a = (const float*)d_in[8];  const float* b0a = (const float*)d_in[9];
    const float* W0u = (const float*)d_in[10]; const float* b0u = (const float*)d_in[11];
    const float* W1a = (const float*)d_in[12]; const float* b1a = (const float*)d_in[13];
    const float* W1u = (const float*)d_in[14]; const float* b1u = (const float*)d_in[15];
    const float* Wc  = (const float*)d_in[16]; const float* bc  = (const float*)d_in[17];
    const float* Aaff0 = (const float*)d_in[18];
    const float* Aaff1 = (const float*)d_in[19];

    const long long TSZ = 16777216LL;
    float* T1 = (float*)d_ws;
    float* T2 = T1 + TSZ;
    float* T3 = T2 + TSZ;
    float* T4 = T3 + TSZ;

    float* S    = (float*)d_out;
    float* inv1 = S;
    float* inv2 = S + 8192;

    const long long sP = 65536, sX = 524288;
    const bool F = false, T = true;

    colnorm_k<<<32, 256, 0, stream>>>(A1, inv1);
    colnorm_k<<<32, 256, 0, stream>>>(A2, inv2);

    // ---- gconv layer 0 ----
    gemm(stream, F, F, feat1, W0a, T3, 8192, 2048, 1024, 0, 0, 0, 1, b0a, inv1, 1, 0);
    gemm(stream, F, F, feat1, W0u, T1, 8192, 2048, 1024, 0, 0, 0, 1, b0u, nullptr, 1, 0);
    gemm(stream, F, F, A1, T3, T1, 256, 2048, 256, sP, sX, sX, 32, nullptr, nullptr, 0, 1);
    gemm(stream, F, F, feat2, W0a, T3, 8192, 2048, 1024, 0, 0, 0, 1, b0a, inv2, 1, 0);
    gemm(stream, F, F, feat2, W0u, T2, 8192, 2048, 1024, 0, 0, 0, 1, b0u, nullptr, 1, 0);
    gemm(stream, F, F, A2, T3, T2, 256, 2048, 256, sP, sX, sX, 32, nullptr, nullptr, 0, 1);

    // ---- affinity 0: S = (emb1 @ Aaff0) @ emb2^T  (fp64 accumulate) ----
    gemm(stream, F, F, T1, Aaff0, T3, 8192, 2048, 2048, 0, 0, 0, 1, nullptr, nullptr, 0, 0);
    gemm_bt_f64<<<dim3(4, 4, 32), 256, 0, stream>>>(T3, T2, S, 2048, sX, sX, sP);

    sinkhorn(stream, S, n1);

    // ---- cross-graph update ----
    gemm(stream, F, F, S, T2, T4, 256, 2048, 256, sP, sX, sX, 32, nullptr, nullptr, 0, 0);
    gemm(stream, F, F, T1, Wc, T3, 8192, 2048, 2048, 0, 0, 0, 1, bc, nullptr, 0, 0);
    gemm(stream, F, F, T4, Wc + 4194304, T3, 8192, 2048, 2048, 0, 0, 0, 1, nullptr, nullptr, 0, 1);
    gemm(stream, T, F, S, T1, T4, 256, 2048, 256, sP, sX, sX, 32, nullptr, nullptr, 0, 0);
    gemm(stream, F, F, T2, Wc, T1, 8192, 2048, 2048, 0, 0, 0, 1, bc, nullptr, 0, 0);
    gemm(stream, F, F, T4, Wc + 4194304, T1, 8192, 2048, 2048, 0, 0, 0, 1, nullptr, nullptr, 0, 1);

    // ---- window-2 colnorm ----
    colnorm_k<<<32, 256, 0, stream>>>(A1, inv1);
    colnorm_k<<<32, 256, 0, stream>>>(A2, inv2);

    // ---- gconv layer 1 ----
    gemm(stream, F, F, T3, W1a, T2, 8192, 2048, 2048, 0, 0, 0, 1, b1a, inv1, 1, 0);
    gemm(stream, F, F, T3, W1u, T4, 8192, 2048, 2048, 0, 0, 0, 1, b1u, nullptr, 1, 0);
    gemm(stream, F, F, A1, T2, T4, 256, 2048, 256, sP, sX, sX, 32, nullptr, nullptr, 0, 1);
    gemm(stream, F, F, T1, W1a, T2, 8192, 2048, 2048, 0, 0, 0, 1, b1a, inv2, 1, 0);
    gemm(stream, F, F, T1, W1u, T3, 8192, 2048, 2048, 0, 0, 0, 1, b1u, nullptr, 1, 0);
    gemm(stream, F, F, A2, T2, T3, 256, 2048, 256, sP, sX, sX, 32, nullptr, nullptr, 0, 1);

    // ---- affinity 1: S = (emb1f @ Aaff1) @ emb2f^T  (fp64 accumulate) ----
    gemm(stream, F, F, T4, Aaff1, T1, 8192, 2048, 2048, 0, 0, 0, 1, nullptr, nullptr, 0, 0);
    gemm_bt_f64<<<dim3(4, 4, 32), 256, 0, stream>>>(T1, T3, S, 2048, sX, sX, sP);

    // ---- sinkhorn 2 -> final output in d_out ----
    sinkhorn(stream, S, n1);
}

// Round 4
// 5668.986 us; speedup vs baseline: 2.0345x; 2.0345x over previous
//
#include <hip/hip_runtime.h>
#include <math.h>

#define NEGV -1e9f
#define SK_TAU 0.05f

typedef __attribute__((ext_vector_type(4))) float f32x4;
typedef __attribute__((ext_vector_type(8))) short short8;

// =====================================================================
// inv column L1 norm: inv[b*256+m] = 1 / max(sum_n |A[b,n,m]|, 1e-12)
// =====================================================================
__global__ __launch_bounds__(256) void colnorm_k(const float* __restrict__ A,
                                                 float* __restrict__ inv)
{
    int idx = blockIdx.x * 256 + threadIdx.x;
    int b = idx >> 8, m = idx & 255;
    const float* p = A + (long long)b * 65536 + m;
    float s = 0.f;
    #pragma unroll 8
    for (int n = 0; n < 256; ++n) s += fabsf(p[n * 256]);
    inv[idx] = 1.f / fmaxf(s, 1e-12f);
}

// =====================================================================
// bf16 split helpers: x = hi + lo (+ ~2^-17 residual). hi RTN, lo trunc.
// =====================================================================
__device__ inline unsigned bf16rtn(float x) {
    unsigned u = __float_as_uint(x);
    return (u + 0x7FFFu + ((u >> 16) & 1u)) >> 16;
}
__device__ inline void cvt4(const float4 v, short4& h, short4& l) {
    unsigned h0 = bf16rtn(v.x), h1 = bf16rtn(v.y), h2 = bf16rtn(v.z), h3 = bf16rtn(v.w);
    h.x = (short)h0; h.y = (short)h1; h.z = (short)h2; h.w = (short)h3;
    float l0 = v.x - __uint_as_float(h0 << 16);
    float l1 = v.y - __uint_as_float(h1 << 16);
    float l2 = v.z - __uint_as_float(h2 << 16);
    float l3 = v.w - __uint_as_float(h3 << 16);
    l.x = (short)(__float_as_uint(l0) >> 16);
    l.y = (short)(__float_as_uint(l1) >> 16);
    l.z = (short)(__float_as_uint(l2) >> 16);
    l.w = (short)(__float_as_uint(l3) >> 16);
}

// =====================================================================
// Split-bf16 MFMA GEMM (fp32 in/out, fp32 accumulate in MFMA):
//   C = epi( A[M,K] @ B[K,N] ),  A,B row-major, flat (batch=1).
// 2-split: C ~= Ah.Bh + Ah.Bl + Al.Bh  (3x mfma_f32_16x16x32_bf16).
// Block 128x128xBK32, 256 thr (4 waves, 2x2 of 64x64 wave-tiles).
// LDS tiles [row][k] with row stride 36 shorts (conflict-tamed, 8B-aligned).
// Epilogue: (+bias[n]) -> relu -> (*rowscale[row]) -> (+=C | =C)
// M%128==0, N%128==0, K%32==0.
// =====================================================================
#define RS 36   // short stride per LDS tile row

__global__ __launch_bounds__(256, 2) void gemm_bf16s(
    const float* __restrict__ A, const float* __restrict__ B,
    float* __restrict__ C, int M, int N, int K,
    const float* __restrict__ bias, const float* __restrict__ rowscale,
    int relu, int accf)
{
    __shared__ short Ah[128 * RS];
    __shared__ short Al[128 * RS];
    __shared__ short Bh[128 * RS];
    __shared__ short Bl[128 * RS];

    const int tid = threadIdx.x;
    const int wave = tid >> 6, L = tid & 63;
    const int m0 = blockIdx.y * 128, n0 = blockIdx.x * 128;
    const int wm = (wave & 1) * 64, wn = (wave >> 1) * 64;

    // staging maps
    const int arow = tid & 127;            // A tile row
    const int agrp = (tid >> 7) * 4;       // float4 group base (0 or 4)
    const int bn   = tid & 127;            // B tile col (n)
    const int bkb  = (tid >> 7) * 4;       // k base (0 or 4)

    const float* aptr0 = A + (long long)(m0 + arow) * K + agrp * 4;
    const float* bptr0 = B + (long long)bkb * N + n0 + bn;

    f32x4 acc[4][4];
    #pragma unroll
    for (int i = 0; i < 4; ++i)
        #pragma unroll
        for (int j = 0; j < 4; ++j)
            acc[i][j] = (f32x4){0.f, 0.f, 0.f, 0.f};

    // ---- prologue: load + convert k0 = 0 ----
    float4 araw[4];
    float  braw[16];
    #pragma unroll
    for (int i = 0; i < 4; ++i) araw[i] = ((const float4*)aptr0)[i];
    #pragma unroll
    for (int g = 0; g < 4; ++g)
        #pragma unroll
        for (int i = 0; i < 4; ++i)
            braw[g * 4 + i] = bptr0[(g * 8 + i) * N];

    short4 ah4[4], al4[4], bh4[4], bl4[4];
    #pragma unroll
    for (int i = 0; i < 4; ++i) cvt4(araw[i], ah4[i], al4[i]);
    #pragma unroll
    for (int g = 0; g < 4; ++g) {
        float4 v = {braw[g * 4 + 0], braw[g * 4 + 1], braw[g * 4 + 2], braw[g * 4 + 3]};
        cvt4(v, bh4[g], bl4[g]);
    }

    for (int k0 = 0; k0 < K; k0 += 32) {
        __syncthreads();   // previous MFMA done reading LDS
        #pragma unroll
        for (int i = 0; i < 4; ++i) {
            *(short4*)&Ah[arow * RS + (agrp + i) * 4] = ah4[i];
            *(short4*)&Al[arow * RS + (agrp + i) * 4] = al4[i];
        }
        #pragma unroll
        for (int g = 0; g < 4; ++g) {
            *(short4*)&Bh[bn * RS + bkb + g * 8] = bh4[g];
            *(short4*)&Bl[bn * RS + bkb + g * 8] = bl4[g];
        }
        __syncthreads();

        // ---- prefetch next k-panel (VMEM overlaps MFMA below) ----
        const bool more = (k0 + 32) < K;
        if (more) {
            const float* ap = aptr0 + (k0 + 32);
            const float* bp = bptr0 + (long long)(k0 + 32) * N;
            #pragma unroll
            for (int i = 0; i < 4; ++i) araw[i] = ((const float4*)ap)[i];
            #pragma unroll
            for (int g = 0; g < 4; ++g)
                #pragma unroll
                for (int i = 0; i < 4; ++i)
                    braw[g * 4 + i] = bp[(g * 8 + i) * N];
        }

        // ---- fragments + 48 MFMA ----
        short8 AF[4], ALF[4], BF[4], BLF[4];
        {
            int mb = (wm + (L & 15)) * RS + (L >> 4) * 8;
            int nb = (wn + (L & 15)) * RS + (L >> 4) * 8;
            #pragma unroll
            for (int t = 0; t < 4; ++t) {
                int ao = mb + t * 16 * RS;
                *(short4*)&AF[t]        = *(short4*)&Ah[ao];
                *((short4*)&AF[t] + 1)  = *(short4*)&Ah[ao + 4];
                *(short4*)&ALF[t]       = *(short4*)&Al[ao];
                *((short4*)&ALF[t] + 1) = *(short4*)&Al[ao + 4];
                int bo = nb + t * 16 * RS;
                *(short4*)&BF[t]        = *(short4*)&Bh[bo];
                *((short4*)&BF[t] + 1)  = *(short4*)&Bh[bo + 4];
                *(short4*)&BLF[t]       = *(short4*)&Bl[bo];
                *((short4*)&BLF[t] + 1) = *(short4*)&Bl[bo + 4];
            }
        }
        #pragma unroll
        for (int ti = 0; ti < 4; ++ti)
            #pragma unroll
            for (int tj = 0; tj < 4; ++tj) {
                acc[ti][tj] = __builtin_amdgcn_mfma_f32_16x16x32_bf16(AF[ti],  BF[tj],  acc[ti][tj], 0, 0, 0);
                acc[ti][tj] = __builtin_amdgcn_mfma_f32_16x16x32_bf16(AF[ti],  BLF[tj], acc[ti][tj], 0, 0, 0);
                acc[ti][tj] = __builtin_amdgcn_mfma_f32_16x16x32_bf16(ALF[ti], BF[tj],  acc[ti][tj], 0, 0, 0);
            }

        // ---- convert prefetched panel (after MFMA; waits on VMEM here) ----
        if (more) {
            #pragma unroll
            for (int i = 0; i < 4; ++i) cvt4(araw[i], ah4[i], al4[i]);
            #pragma unroll
            for (int g = 0; g < 4; ++g) {
                float4 v = {braw[g * 4 + 0], braw[g * 4 + 1], braw[g * 4 + 2], braw[g * 4 + 3]};
                cvt4(v, bh4[g], bl4[g]);
            }
        }
    }

    // ---- epilogue: C/D layout col = lane&15, row = (lane>>4)*4 + reg ----
    const int lcol = L & 15, lrow = (L >> 4) * 4;
    float bv[4];
    #pragma unroll
    for (int tj = 0; tj < 4; ++tj)
        bv[tj] = bias ? bias[n0 + wn + tj * 16 + lcol] : 0.f;

    #pragma unroll
    for (int ti = 0; ti < 4; ++ti) {
        #pragma unroll
        for (int r = 0; r < 4; ++r) {
            int grow = m0 + wm + ti * 16 + lrow + r;
            float rs = rowscale ? rowscale[grow] : 1.f;
            float* crow = C + (long long)grow * N;
            #pragma unroll
            for (int tj = 0; tj < 4; ++tj) {
                int gcol = n0 + wn + tj * 16 + lcol;
                float v = acc[ti][tj][r] + bv[tj];
                if (relu) v = fmaxf(v, 0.f);
                v *= rs;
                if (accf) v += crow[gcol];
                crow[gcol] = v;
            }
        }
    }
}

static void gemm_s(hipStream_t st, const float* A, const float* B, float* C,
                   int M, int N, int K,
                   const float* bias, const float* rowscale, int relu, int acc)
{
    dim3 grid(N / 128, M / 128), block(256);
    gemm_bf16s<<<grid, block, 0, st>>>(A, B, C, M, N, K, bias, rowscale, relu, acc);
}

// =====================================================================
// fp32 VALU GEMM (kept for the batched 256-row GEMMs): C[z]=epi(A[z]@B[z])
// =====================================================================
#define BMt 128
#define BNt 128
#define BKt 16
#define LDT 132

template <bool TA, bool TB>
__global__ __launch_bounds__(256, 2) void gemm_k(
    const float* __restrict__ A, const float* __restrict__ B,
    float* __restrict__ C, int M, int N, int K,
    long long sA, long long sB, long long sC,
    const float* __restrict__ bias, const float* __restrict__ rowscale,
    int relu, int acc)
{
    __shared__ float As[BKt][LDT];
    __shared__ float Bs[BKt][LDT];

    int z = blockIdx.z;
    A += (long long)z * sA;
    B += (long long)z * sB;
    C += (long long)z * sC;

    int n0 = blockIdx.x * BNt;
    int m0 = blockIdx.y * BMt;
    int tid = threadIdx.x;
    int tx = tid & 15;
    int ty = tid >> 4;

    const int ldA = TA ? M : K;
    const int ldB = TB ? K : N;

    float accv[8][8];
    #pragma unroll
    for (int i = 0; i < 8; ++i)
        #pragma unroll
        for (int j = 0; j < 8; ++j) accv[i][j] = 0.f;

    for (int k0 = 0; k0 < K; k0 += BKt) {
        if (!TA) {
            #pragma unroll
            for (int i = 0; i < 2; ++i) {
                int lin = tid + i * 256;
                int r  = lin >> 2;
                int c4 = (lin & 3) * 4;
                const float4 v = *(const float4*)(A + (long long)(m0 + r) * ldA + k0 + c4);
                As[c4 + 0][r] = v.x; As[c4 + 1][r] = v.y;
                As[c4 + 2][r] = v.z; As[c4 + 3][r] = v.w;
            }
        } else {
            #pragma unroll
            for (int i = 0; i < 2; ++i) {
                int lin = tid + i * 256;
                int kk = lin >> 5;
                int m4 = (lin & 31) * 4;
                *(float4*)&As[kk][m4] =
                    *(const float4*)(A + (long long)(k0 + kk) * ldA + m0 + m4);
            }
        }
        if (!TB) {
            #pragma unroll
            for (int i = 0; i < 2; ++i) {
                int lin = tid + i * 256;
                int kk = lin >> 5;
                int n4 = (lin & 31) * 4;
                *(float4*)&Bs[kk][n4] =
                    *(const float4*)(B + (long long)(k0 + kk) * ldB + n0 + n4);
            }
        } else {
            #pragma unroll
            for (int i = 0; i < 2; ++i) {
                int lin = tid + i * 256;
                int r  = lin >> 2;
                int c4 = (lin & 3) * 4;
                const float4 v = *(const float4*)(B + (long long)(n0 + r) * ldB + k0 + c4);
                Bs[c4 + 0][r] = v.x; Bs[c4 + 1][r] = v.y;
                Bs[c4 + 2][r] = v.z; Bs[c4 + 3][r] = v.w;
            }
        }
        __syncthreads();

        #pragma unroll
        for (int kk = 0; kk < BKt; ++kk) {
            float a[8], b[8];
            *(float4*)&a[0] = *(const float4*)&As[kk][ty * 8];
            *(float4*)&a[4] = *(const float4*)&As[kk][ty * 8 + 4];
            *(float4*)&b[0] = *(const float4*)&Bs[kk][tx * 8];
            *(float4*)&b[4] = *(const float4*)&Bs[kk][tx * 8 + 4];
            #pragma unroll
            for (int i = 0; i < 8; ++i)
                #pragma unroll
                for (int j = 0; j < 8; ++j)
                    accv[i][j] = fmaf(a[i], b[j], accv[i][j]);
        }
        __syncthreads();
    }

    #pragma unroll
    for (int i = 0; i < 8; ++i) {
        int row = m0 + ty * 8 + i;
        float rs = rowscale ? rowscale[row] : 1.f;
        float* crow = C + (long long)row * N;
        #pragma unroll
        for (int jj = 0; jj < 2; ++jj) {
            int col = n0 + tx * 8 + jj * 4;
            float4 v;
            v.x = accv[i][jj * 4 + 0]; v.y = accv[i][jj * 4 + 1];
            v.z = accv[i][jj * 4 + 2]; v.w = accv[i][jj * 4 + 3];
            if (bias) {
                v.x += bias[col + 0]; v.y += bias[col + 1];
                v.z += bias[col + 2]; v.w += bias[col + 3];
            }
            if (relu) {
                v.x = fmaxf(v.x, 0.f); v.y = fmaxf(v.y, 0.f);
                v.z = fmaxf(v.z, 0.f); v.w = fmaxf(v.w, 0.f);
            }
            v.x *= rs; v.y *= rs; v.z *= rs; v.w *= rs;
            if (acc) {
                float4 o = *(const float4*)(crow + col);
                v.x += o.x; v.y += o.y; v.z += o.z; v.w += o.w;
            }
            *(float4*)(crow + col) = v;
        }
    }
}

static void gemm(hipStream_t st, bool ta, bool tb,
                 const float* A, const float* B, float* C,
                 int M, int N, int K,
                 long long sA, long long sB, long long sC, int batch,
                 const float* bias, const float* rowscale, int relu, int acc)
{
    dim3 grid(N / BNt, M / BMt, batch), block(256);
    if (!ta && !tb)
        gemm_k<false, false><<<grid, block, 0, st>>>(A, B, C, M, N, K, sA, sB, sC, bias, rowscale, relu, acc);
    else if (ta && !tb)
        gemm_k<true, false><<<grid, block, 0, st>>>(A, B, C, M, N, K, sA, sB, sC, bias, rowscale, relu, acc);
    else
        gemm_k<false, true><<<grid, block, 0, st>>>(A, B, C, M, N, K, sA, sB, sC, bias, rowscale, relu, acc);
}

// =====================================================================
// fp64-accumulate batched GEMM for affinity scores: C = A @ B^T (K=2048).
// =====================================================================
#define L2P 65

__global__ __launch_bounds__(256) void gemm_bt_f64(
    const float* __restrict__ A, const float* __restrict__ B,
    float* __restrict__ C, int K,
    long long sA, long long sB, long long sC)
{
    __shared__ float As[BKt][L2P];
    __shared__ float Bs[BKt][L2P];

    int z = blockIdx.z;
    A += (long long)z * sA;
    B += (long long)z * sB;
    C += (long long)z * sC;

    int n0 = blockIdx.x * 64;
    int m0 = blockIdx.y * 64;
    int tid = threadIdx.x;
    int tx = tid & 15;
    int ty = tid >> 4;

    double acc[4][4];
    #pragma unroll
    for (int i = 0; i < 4; ++i)
        #pragma unroll
        for (int j = 0; j < 4; ++j) acc[i][j] = 0.0;

    int r  = tid >> 2;
    int c4 = (tid & 3) * 4;

    for (int k0 = 0; k0 < K; k0 += BKt) {
        {
            const float4 v = *(const float4*)(A + (long long)(m0 + r) * K + k0 + c4);
            As[c4 + 0][r] = v.x; As[c4 + 1][r] = v.y;
            As[c4 + 2][r] = v.z; As[c4 + 3][r] = v.w;
        }
        {
            const float4 v = *(const float4*)(B + (long long)(n0 + r) * K + k0 + c4);
            Bs[c4 + 0][r] = v.x; Bs[c4 + 1][r] = v.y;
            Bs[c4 + 2][r] = v.z; Bs[c4 + 3][r] = v.w;
        }
        __syncthreads();

        #pragma unroll
        for (int kk = 0; kk < BKt; ++kk) {
            double a[4], b[4];
            #pragma unroll
            for (int i = 0; i < 4; ++i) a[i] = (double)As[kk][ty + 16 * i];
            #pragma unroll
            for (int j = 0; j < 4; ++j) b[j] = (double)Bs[kk][tx + 16 * j];
            #pragma unroll
            for (int i = 0; i < 4; ++i)
                #pragma unroll
                for (int j = 0; j < 4; ++j)
                    acc[i][j] = fma(a[i], b[j], acc[i][j]);
        }
        __syncthreads();
    }

    #pragma unroll
    for (int i = 0; i < 4; ++i) {
        int row = m0 + ty + 16 * i;
        #pragma unroll
        for (int j = 0; j < 4; ++j) {
            int col = n0 + tx + 16 * j;
            C[(long long)row * 256 + col] = (float)acc[i][j];
        }
    }
}

// =====================================================================
// Sinkhorn
// =====================================================================
__global__ __launch_bounds__(256) void sk_row(float* __restrict__ S,
                                              const int* __restrict__ n1, int init)
{
    int r = blockIdx.x * 4 + (threadIdx.x >> 6);
    int lane = threadIdx.x & 63;
    int b = r >> 8, n = r & 255;
    float* p = S + (long long)r * 256;
    int lim = n1[b];
    if (n >= lim) {
        float4 neg = {NEGV, NEGV, NEGV, NEGV};
        *(float4*)(p + lane * 4) = neg;
        return;
    }
    float4 v = *(const float4*)(p + lane * 4);
    if (init) {
        v.x /= SK_TAU; v.y /= SK_TAU; v.z /= SK_TAU; v.w /= SK_TAU;
    }
    float m = fmaxf(fmaxf(v.x, v.y), fmaxf(v.z, v.w));
    #pragma unroll
    for (int off = 1; off < 64; off <<= 1) m = fmaxf(m, __shfl_xor(m, off));
    float s = expf(v.x - m) + expf(v.y - m) + expf(v.z - m) + expf(v.w - m);
    #pragma unroll
    for (int off = 1; off < 64; off <<= 1) s += __shfl_xor(s, off);
    float lse = m + logf(s);
    v.x -= lse; v.y -= lse; v.z -= lse; v.w -= lse;
    *(float4*)(p + lane * 4) = v;
}

__global__ __launch_bounds__(64) void sk_col(float* __restrict__ S,
                                             const int* __restrict__ n1, int final_)
{
    int b = blockIdx.y;
    int m = blockIdx.x * 64 + threadIdx.x;
    float* base = S + (long long)b * 65536;
    int lim = n1[b];
    float vmax = -3.4e38f;
    for (int n = 0; n < 256; ++n) vmax = fmaxf(vmax, base[n * 256 + m]);
    float sum = 0.f;
    for (int n = 0; n < 256; ++n) sum += expf(base[n * 256 + m] - vmax);
    float lse = vmax + logf(sum);
    if (final_) {
        for (int n = 0; n < 256; ++n) {
            float x = base[n * 256 + m];
            base[n * 256 + m] = (n < lim) ? expf(x - lse) : 0.f;
        }
    } else {
        for (int n = 0; n < 256; ++n) {
            float x = base[n * 256 + m];
            base[n * 256 + m] = (n < lim) ? (x - lse) : NEGV;
        }
    }
}

static void sinkhorn(hipStream_t st, float* S, const int* n1)
{
    sk_row<<<2048, 256, 0, st>>>(S, n1, 1);
    for (int it = 1; it < 10; ++it) {
        if (it & 1)
            sk_col<<<dim3(4, 32), 64, 0, st>>>(S, n1, it == 9);
        else
            sk_row<<<2048, 256, 0, st>>>(S, n1, 0);
    }
}

// =====================================================================
// driver — d_ws budget EXACTLY 4 x 64 MiB; score buffer in d_out.
// =====================================================================
extern "C" void kernel_launch(void* const* d_in, const int* in_sizes, int n_in,
                              void* d_out, int out_size, void* d_ws, size_t ws_size,
                              hipStream_t stream)
{
    const float* feat1 = (const float*)d_in[0];
    const float* feat2 = (const float*)d_in[1];
    const float* A1    = (const float*)d_in[2];
    const float* A2    = (const float*)d_in[3];
    const int*   n1    = (const int*)d_in[4];
    const float* W0a = (const float*)d_in[8];  const float* b0a = (const float*)d_in[9];
    const float* W0u = (const float*)d_in[10]; const float* b0u = (const float*)d_in[11];
    const float* W1a = (const float*)d_in[12]; const float* b1a = (const float*)d_in[13];
    const float* W1u = (const float*)d_in[14]; const float* b1u = (const float*)d_in[15];
    const float* Wc  = (const float*)d_in[16]; const float* bc  = (const float*)d_in[17];
    const float* Aaff0 = (const float*)d_in[18];
    const float* Aaff1 = (const float*)d_in[19];

    const long long TSZ = 16777216LL;
    float* T1 = (float*)d_ws;
    float* T2 = T1 + TSZ;
    float* T3 = T2 + TSZ;
    float* T4 = T3 + TSZ;

    float* S    = (float*)d_out;
    float* inv1 = S;
    float* inv2 = S + 8192;

    const long long sP = 65536, sX = 524288;
    const bool F = false, T = true;

    colnorm_k<<<32, 256, 0, stream>>>(A1, inv1);
    colnorm_k<<<32, 256, 0, stream>>>(A2, inv2);

    // ---- gconv layer 0 (flat GEMMs -> split-bf16 MFMA) ----
    gemm_s(stream, feat1, W0a, T3, 8192, 2048, 1024, b0a, inv1, 1, 0);
    gemm_s(stream, feat1, W0u, T1, 8192, 2048, 1024, b0u, nullptr, 1, 0);
    gemm(stream, F, F, A1, T3, T1, 256, 2048, 256, sP, sX, sX, 32, nullptr, nullptr, 0, 1);
    gemm_s(stream, feat2, W0a, T3, 8192, 2048, 1024, b0a, inv2, 1, 0);
    gemm_s(stream, feat2, W0u, T2, 8192, 2048, 1024, b0u, nullptr, 1, 0);
    gemm(stream, F, F, A2, T3, T2, 256, 2048, 256, sP, sX, sX, 32, nullptr, nullptr, 0, 1);

    // ---- affinity 0: S = (emb1 @ Aaff0) @ emb2^T  (fp64 accumulate) ----
    gemm_s(stream, T1, Aaff0, T3, 8192, 2048, 2048, nullptr, nullptr, 0, 0);
    gemm_bt_f64<<<dim3(4, 4, 32), 256, 0, stream>>>(T3, T2, S, 2048, sX, sX, sP);

    sinkhorn(stream, S, n1);

    // ---- cross-graph update ----
    gemm(stream, F, F, S, T2, T4, 256, 2048, 256, sP, sX, sX, 32, nullptr, nullptr, 0, 0);
    gemm_s(stream, T1, Wc, T3, 8192, 2048, 2048, bc, nullptr, 0, 0);
    gemm_s(stream, T4, Wc + 4194304, T3, 8192, 2048, 2048, nullptr, nullptr, 0, 1);
    gemm(stream, T, F, S, T1, T4, 256, 2048, 256, sP, sX, sX, 32, nullptr, nullptr, 0, 0);
    gemm_s(stream, T2, Wc, T1, 8192, 2048, 2048, bc, nullptr, 0, 0);
    gemm_s(stream, T4, Wc + 4194304, T1, 8192, 2048, 2048, nullptr, nullptr, 0, 1);

    // ---- window-2 colnorm ----
    colnorm_k<<<32, 256, 0, stream>>>(A1, inv1);
    colnorm_k<<<32, 256, 0, stream>>>(A2, inv2);

    // ---- gconv layer 1 ----
    gemm_s(stream, T3, W1a, T2, 8192, 2048, 2048, b1a, inv1, 1, 0);
    gemm_s(stream, T3, W1u, T4, 8192, 2048, 2048, b1u, nullptr, 1, 0);
    gemm(stream, F, F, A1, T2, T4, 256, 2048, 256, sP, sX, sX, 32, nullptr, nullptr, 0, 1);
    gemm_s(stream, T1, W1a, T2, 8192, 2048, 2048, b1a, inv2, 1, 0);
    gemm_s(stream, T1, W1u, T3, 8192, 2048, 2048, b1u, nullptr, 1, 0);
    gemm(stream, F, F, A2, T2, T3, 256, 2048, 256, sP, sX, sX, 32, nullptr, nullptr, 0, 1);

    // ---- affinity 1: S = (emb1f @ Aaff1) @ emb2f^T  (fp64 accumulate) ----
    gemm_s(stream, T4, Aaff1, T1, 8192, 2048, 2048, nullptr, nullptr, 0, 0);
    gemm_bt_f64<<<dim3(4, 4, 32), 256, 0, stream>>>(T1, T3, S, 2048, sX, sX, sP);

    // ---- sinkhorn 2 -> final output in d_out ----
    sinkhorn(stream, S, n1);
}